// Round 1
// baseline (366.577 us; speedup 1.0000x reference)
//
#include <hip/hip_runtime.h>

// x: (64, 64, 64, 128) fp32, element strides: b0=524288, i=8192, j=128, c=1
// out0 = FWHT over axis 1 (i), out1 = FWHT over axis 2 (j) of out0.
// Each thread performs a full length-64 FWHT in registers for one fixed
// (b0, other-axis, c) line. Lane index maps to c (innermost) so every
// global load/store is 64 consecutive floats per wave (fully coalesced).

template <int TSTRIDE, int FSTRIDE>
__global__ __launch_bounds__(256) void fwht64_kernel(const float* __restrict__ in,
                                                     float* __restrict__ out) {
    const int tid = blockIdx.x * 256 + threadIdx.x;
    const int c   = tid & 127;          // channel, innermost -> coalesced lanes
    const int m   = (tid >> 7) & 63;    // the non-transformed spatial axis
    const int b0  = tid >> 13;          // batch
    const int base = b0 * (64 * 64 * 128) + m * FSTRIDE + c;

    float v[64];
#pragma unroll
    for (int k = 0; k < 64; ++k)
        v[k] = in[base + k * TSTRIDE];

    // 6 butterfly stages, identical pairing/order to the reference:
    // for h in {1,2,4,8,16,32}: (v[s+t], v[s+t+h]) -> (a+b, a-b)
#pragma unroll
    for (int sh = 0; sh < 6; ++sh) {
        const int h = 1 << sh;
#pragma unroll
        for (int s = 0; s < 64; s += 2 * h) {
#pragma unroll
            for (int t = 0; t < h; ++t) {
                const float a = v[s + t];
                const float b = v[s + t + h];
                v[s + t]     = a + b;
                v[s + t + h] = a - b;
            }
        }
    }

#pragma unroll
    for (int k = 0; k < 64; ++k)
        out[base + k * TSTRIDE] = v[k];
}

extern "C" void kernel_launch(void* const* d_in, const int* in_sizes, int n_in,
                              void* d_out, int out_size, void* d_ws, size_t ws_size,
                              hipStream_t stream) {
    const float* x = (const float*)d_in[0];
    float* out0 = (float*)d_out;                    // trans_im1: 64*64*64*128 floats
    float* out1 = out0 + 64 * 64 * 64 * 128;        // trans_im2

    // 64 (b0) * 64 (other axis) * 128 (c) threads = 524288 -> 2048 blocks of 256
    const int blocks = 2048;

    // Kernel A: transform axis 1 (stride 8192), fixed axis j (stride 128)
    fwht64_kernel<8192, 128><<<blocks, 256, 0, stream>>>(x, out0);
    // Kernel B: transform axis 2 (stride 128), fixed axis i (stride 8192)
    fwht64_kernel<128, 8192><<<blocks, 256, 0, stream>>>(out0, out1);
}